// Round 2
// baseline (156.015 us; speedup 1.0000x reference)
//
#include <hip/hip_runtime.h>
#include <hip/hip_bf16.h>

typedef _Float16 half8 __attribute__((ext_vector_type(8)));
typedef float f32x4 __attribute__((ext_vector_type(4)));

constexpr int KC = 256;      // clusters
constexpr int DD = 64;       // feature dim
constexpr int NN = 262144;   // points
constexpr int GRID = 1024;
constexpr int TILE_COLS = 64;                  // columns per block per iteration (4 waves x 16)
constexpr int ITERS = NN / TILE_COLS / GRID;   // 4

// out[k][n] = alpha[k] - 32*logvar[k] - 0.5*(m2[k] + x2[n] - 2*mu[k].x[n]) * exp(-logvar[k])
//           = A[k] + (cross[k][n] - 0.5*x2[n]) * C[k]
// with A[k] = alpha[k] - 32*logvar[k] - 0.5*m2[k]*C[k],  C[k] = exp(-logvar[k])

__global__ __launch_bounds__(256, 4)
void gmm_ll_kernel(const float* __restrict__ X,
                   const float* __restrict__ mu,
                   const float* __restrict__ logvar,
                   const float* __restrict__ alpha,
                   float* __restrict__ out)
{
    // mu in f16, XOR-swizzled, 256 rows x 128B; then 256 float2 (A,C)
    __shared__ __align__(16) unsigned char smem[KC * 128 + KC * 8];
    float2* AC = (float2*)(smem + KC * 128);

    const int tid = threadIdx.x;

    // ---------- per-block setup: each thread owns one cluster ----------
    {
        const int t = tid;
        const float* mrow = mu + t * DD;
        float m2 = 0.f;
        #pragma unroll
        for (int s = 0; s < 8; ++s) {
            float4 v0 = *(const float4*)(mrow + 8 * s);
            float4 v1 = *(const float4*)(mrow + 8 * s + 4);
            m2 += v0.x*v0.x + v0.y*v0.y + v0.z*v0.z + v0.w*v0.w
                + v1.x*v1.x + v1.y*v1.y + v1.z*v1.z + v1.w*v1.w;
            half8 hch = { (_Float16)v0.x, (_Float16)v0.y, (_Float16)v0.z, (_Float16)v0.w,
                          (_Float16)v1.x, (_Float16)v1.y, (_Float16)v1.z, (_Float16)v1.w };
            // 16B chunk s of row t stored at swizzled slot (s ^ (t&7))
            *(half8*)(smem + t * 128 + ((s ^ (t & 7)) * 16)) = hch;
        }
        float lv = logvar[t];
        float Cv = __expf(-lv);
        float Av = alpha[t] - 32.0f * lv - 0.5f * m2 * Cv;
        AC[t] = make_float2(Av, Cv);
    }
    __syncthreads();

    const int l = tid & 63;
    const int w = tid >> 6;   // wave id 0..3
    const int m = l & 15;     // column-in-tile / A row selector
    const int h = l >> 4;     // 0..3
    const int sw = (m & 7);   // swizzle key for A reads

    for (int it = 0; it < ITERS; ++it) {
        const int tile = blockIdx.x * ITERS + it;
        const int col = tile * TILE_COLS + w * 16 + m;
        const float* xrow = X + (size_t)col * DD;

        // B fragment: lane holds X[col][ h*8 .. h*8+7 ] and X[col][ 32+h*8 .. ]
        float4 a0 = *(const float4*)(xrow + h * 8);
        float4 a1 = *(const float4*)(xrow + h * 8 + 4);
        float4 a2 = *(const float4*)(xrow + 32 + h * 8);
        float4 a3 = *(const float4*)(xrow + 32 + h * 8 + 4);

        half8 xb0 = { (_Float16)a0.x, (_Float16)a0.y, (_Float16)a0.z, (_Float16)a0.w,
                      (_Float16)a1.x, (_Float16)a1.y, (_Float16)a1.z, (_Float16)a1.w };
        half8 xb1 = { (_Float16)a2.x, (_Float16)a2.y, (_Float16)a2.z, (_Float16)a2.w,
                      (_Float16)a3.x, (_Float16)a3.y, (_Float16)a3.z, (_Float16)a3.w };

        // fp32-exact x2: partial (16 elems) then reduce across the 4 lanes sharing this col
        float p = a0.x*a0.x + a0.y*a0.y + a0.z*a0.z + a0.w*a0.w
                + a1.x*a1.x + a1.y*a1.y + a1.z*a1.z + a1.w*a1.w
                + a2.x*a2.x + a2.y*a2.y + a2.z*a2.z + a2.w*a2.w
                + a3.x*a3.x + a3.y*a3.y + a3.z*a3.z + a3.w*a3.w;
        p += __shfl_xor(p, 16, 64);
        p += __shfl_xor(p, 32, 64);
        const float halfx2 = 0.5f * p;

        float* pout = out + (size_t)(h * 4) * NN + col;

        #pragma unroll
        for (int c = 0; c < 16; ++c) {
            // A fragment: row = c*16 + m, k-chunk = h (d 0..31) / h+4 (d 32..63)
            const unsigned rbase = (unsigned)(c * 16 + m) * 128u;
            half8 af0 = *(const half8*)(smem + rbase + (( h      ^ sw) * 16));
            half8 af1 = *(const half8*)(smem + rbase + (((h + 4) ^ sw) * 16));

            f32x4 acc = {0.f, 0.f, 0.f, 0.f};
            acc = __builtin_amdgcn_mfma_f32_16x16x32_f16(af0, xb0, acc, 0, 0, 0);
            acc = __builtin_amdgcn_mfma_f32_16x16x32_f16(af1, xb1, acc, 0, 0, 0);

            // D layout: col = lane&15, row = (lane>>4)*4 + i
            #pragma unroll
            for (int i = 0; i < 4; ++i) {
                const int k = c * 16 + h * 4 + i;
                const float2 ac = AC[k];
                pout[(size_t)(c * 16 + i) * NN] = ac.x + (acc[i] - halfx2) * ac.y;
            }
        }
    }
}

extern "C" void kernel_launch(void* const* d_in, const int* in_sizes, int n_in,
                              void* d_out, int out_size, void* d_ws, size_t ws_size,
                              hipStream_t stream)
{
    const float* X  = (const float*)d_in[0];
    const float* mu = (const float*)d_in[1];
    const float* lv = (const float*)d_in[2];
    const float* al = (const float*)d_in[3];
    float* out = (float*)d_out;
    gmm_ll_kernel<<<GRID, 256, 0, stream>>>(X, mu, lv, al, out);
}

// Round 3
// 78.446 us; speedup vs baseline: 1.9888x; 1.9888x over previous
//
#include <hip/hip_runtime.h>
#include <hip/hip_bf16.h>

typedef _Float16 half8 __attribute__((ext_vector_type(8)));
typedef float f32x16 __attribute__((ext_vector_type(16)));

constexpr int KC = 256;      // clusters
constexpr int DD = 64;       // feature dim
constexpr int NN = 262144;   // points
constexpr int GRID = 1024;
constexpr int ITERS = 2;     // 128 cols per block-iteration (4 waves x 32)

// out[k][n] = A[k] + (mu[k].x[n] - 0.5*x2[n]) * C[k]
// A[k] = alpha[k] - 32*logvar[k] - 0.5*m2[k]*C[k],  C[k] = exp(-logvar[k])

__global__ __launch_bounds__(256, 4)
void gmm_ll_kernel(const float* __restrict__ X,
                   const float* __restrict__ mu,
                   const float* __restrict__ logvar,
                   const float* __restrict__ alpha,
                   float* __restrict__ out)
{
    // mu in f16, XOR-swizzled chunks: row r (128 B = 8 chunks), chunk s at slot s^(r&7)
    __shared__ __align__(16) unsigned char smu[KC * 128];
    __shared__ float2 AC[KC];

    const int tid = threadIdx.x;

    // ---------- setup: thread t owns cluster t ----------
    {
        const float* mrow = mu + tid * DD;
        float m2 = 0.f;
        #pragma unroll
        for (int s = 0; s < 8; ++s) {
            float4 v0 = *(const float4*)(mrow + 8 * s);
            float4 v1 = *(const float4*)(mrow + 8 * s + 4);
            m2 += v0.x*v0.x + v0.y*v0.y + v0.z*v0.z + v0.w*v0.w
                + v1.x*v1.x + v1.y*v1.y + v1.z*v1.z + v1.w*v1.w;
            half8 hch = { (_Float16)v0.x, (_Float16)v0.y, (_Float16)v0.z, (_Float16)v0.w,
                          (_Float16)v1.x, (_Float16)v1.y, (_Float16)v1.z, (_Float16)v1.w };
            *(half8*)(smu + tid * 128 + ((s ^ (tid & 7)) * 16)) = hch;
        }
        float lv = logvar[tid];
        float Cv = __expf(-lv);
        AC[tid] = make_float2(alpha[tid] - 32.0f * lv - 0.5f * m2 * Cv, Cv);
    }
    __syncthreads();

    const int l = tid & 63;
    const int w = tid >> 6;   // wave 0..3
    const int q = l & 31;     // column within wave tile / mu row selector
    const int h = l >> 5;     // k-half selector

    for (int it = 0; it < ITERS; ++it) {
        const int colb = (blockIdx.x * ITERS + it) * 128 + w * 32;
        const int col  = colb + q;
        const float* xr = X + (size_t)col * DD;

        // B fragments: lane holds X[col][16*kk + 8*h .. +7] for kk=0..3
        half8 bf[4];
        float p = 0.f;
        #pragma unroll
        for (int kk = 0; kk < 4; ++kk) {
            float4 v0 = *(const float4*)(xr + kk * 16 + h * 8);
            float4 v1 = *(const float4*)(xr + kk * 16 + h * 8 + 4);
            p += v0.x*v0.x + v0.y*v0.y + v0.z*v0.z + v0.w*v0.w
               + v1.x*v1.x + v1.y*v1.y + v1.z*v1.z + v1.w*v1.w;
            bf[kk] = { (_Float16)v0.x, (_Float16)v0.y, (_Float16)v0.z, (_Float16)v0.w,
                       (_Float16)v1.x, (_Float16)v1.y, (_Float16)v1.z, (_Float16)v1.w };
        }
        // full ||x||^2 in fp32: partner lane (l^32) holds the other k-half
        p += __shfl_xor(p, 32, 64);
        const float hx2 = 0.5f * p;

        #pragma unroll 2
        for (int c = 0; c < 8; ++c) {
            f32x16 acc = {0.f,0.f,0.f,0.f,0.f,0.f,0.f,0.f,
                          0.f,0.f,0.f,0.f,0.f,0.f,0.f,0.f};
            const int r = 32 * c + q;            // mu row this lane feeds
            const unsigned rbase = (unsigned)r * 128u;
            const unsigned sw = (unsigned)(q & 7);
            #pragma unroll
            for (int kk = 0; kk < 4; ++kk) {
                // A frag: row = lane&31, k = 8*(lane>>5)+e  -> chunk 2*kk + h
                half8 af = *(const half8*)(smu + rbase + ((((unsigned)(2*kk + h)) ^ sw) * 16));
                acc = __builtin_amdgcn_mfma_f32_32x32x16_f16(af, bf[kk], acc, 0, 0, 0);
            }
            // D layout: col = lane&31, row = (reg&3) + 8*(reg>>2) + 4*(lane>>5)
            // each store: 2 full 128-B lines (32 consecutive cols per k-row)
            #pragma unroll
            for (int g = 0; g < 4; ++g) {
                const int Rb = 32 * c + 8 * g + 4 * h;
                #pragma unroll
                for (int j = 0; j < 4; ++j) {
                    const float2 ac = AC[Rb + j];
                    out[(size_t)(Rb + j) * NN + col] = ac.x + (acc[4 * g + j] - hx2) * ac.y;
                }
            }
        }
    }
}

extern "C" void kernel_launch(void* const* d_in, const int* in_sizes, int n_in,
                              void* d_out, int out_size, void* d_ws, size_t ws_size,
                              hipStream_t stream)
{
    const float* X  = (const float*)d_in[0];
    const float* mu = (const float*)d_in[1];
    const float* lv = (const float*)d_in[2];
    const float* al = (const float*)d_in[3];
    float* out = (float*)d_out;
    gmm_ll_kernel<<<GRID, 256, 0, stream>>>(X, mu, lv, al, out);
}